// Round 1
// baseline (135.149 us; speedup 1.0000x reference)
//
#include <hip/hip_runtime.h>

// BoxFilter: separable clamped box-SUM, radius 4, on (32,8,512,512) fp32.
// out[i][j] = sum over x[max(0,i-4)..min(511,i+4)][max(0,j-4)..min(511,j+4)]
// (cumsum-diff in the reference == clamped sliding-window sum).
//
// Fused single pass: vertical running-window sum in registers (float4/thread),
// horizontal 9-tap sum via a zero-padded, double-buffered LDS row.

constexpr int H   = 512;
constexpr int W   = 512;
constexpr int RAD = 4;     // fixed by setup_inputs (r = 4)
constexpr int TH  = 64;    // output rows per block (strip height)
constexpr int NT  = W / 4; // 128 threads, one float4 column-group each
constexpr int PADW = W + 2 * RAD; // 520 floats per padded LDS row

__global__ __launch_bounds__(NT)
void BoxFilter_90331752169653_kernel(const float* __restrict__ x,
                                     float* __restrict__ out) {
    __shared__ float rows[2][PADW];

    const int img   = blockIdx.y;
    const int strip = blockIdx.x;
    const int R0    = strip * TH;
    const int t     = threadIdx.x;

    const float4* __restrict__ x4 = (const float4*)(x + (size_t)img * H * W);
    float4* __restrict__ o4       = (float4*)(out + (size_t)img * H * W);

    // zero the RAD-wide pads on both sides of both row buffers (written once)
    if (t < RAD) {
        rows[0][t] = 0.f; rows[0][W + RAD + t] = 0.f;
        rows[1][t] = 0.f; rows[1][W + RAD + t] = 0.f;
    }

    // ---- vertical clamped running-window sum, one float4 per thread ----
    float4 s; s.x = s.y = s.z = s.w = 0.f;
    {
        const int k0 = (R0 - RAD < 0) ? 0 : (R0 - RAD); // R0+RAD <= 511 always
        for (int k = k0; k <= R0 + RAD; ++k) {
            float4 a = x4[k * NT + t];
            s.x += a.x; s.y += a.y; s.z += a.z; s.w += a.w;
        }
    }

    for (int i = R0; i < R0 + TH; ++i) {
        if (i > R0) {
            if (i + RAD < H) {            // uniform branch (last strip only)
                float4 a = x4[(i + RAD) * NT + t];
                s.x += a.x; s.y += a.y; s.z += a.z; s.w += a.w;
            }
            if (i - RAD - 1 >= 0) {       // uniform branch (first strip only)
                float4 b = x4[(i - RAD - 1) * NT + t];
                s.x -= b.x; s.y -= b.y; s.z -= b.z; s.w -= b.w;
            }
        }

        // stage vertical-sum row in padded LDS (double-buffered: one barrier/row)
        float* rw = rows[i & 1];
        *(float4*)&rw[4 * t + RAD] = s;
        __syncthreads();

        // ---- horizontal 9-tap sum: neighbors from LDS, middle from register ----
        const float* rr = rows[i & 1];
        float4 A = *(const float4*)&rr[4 * t];           // v[j0-4 .. j0-1]
        float4 C = *(const float4*)&rr[4 * t + RAD + 4]; // v[j0+4 .. j0+7]
        float o0 = ((A.x + A.y) + (A.z + A.w)) + ((s.x + s.y) + (s.z + s.w)) + C.x;
        float o1 = o0 - A.x + C.y;
        float o2 = o1 - A.y + C.z;
        float o3 = o2 - A.z + C.w;
        o4[(size_t)i * NT + t] = make_float4(o0, o1, o2, o3);
        // no second barrier needed: next write goes to the other buffer, and the
        // i+2 overwrite of this buffer is ordered by the barrier at i+1.
    }
}

extern "C" void kernel_launch(void* const* d_in, const int* in_sizes, int n_in,
                              void* d_out, int out_size, void* d_ws, size_t ws_size,
                              hipStream_t stream) {
    const float* x = (const float*)d_in[0];
    float* out    = (float*)d_out;
    const int n_img = in_sizes[0] / (H * W); // 32*8 = 256 images
    dim3 grid(H / TH, n_img);
    BoxFilter_90331752169653_kernel<<<grid, NT, 0, stream>>>(x, out);
}